// Round 11
// baseline (197.603 us; speedup 1.0000x reference)
//
#include <hip/hip_runtime.h>
#include <hip/hip_bf16.h>
#include <math.h>

#define NQ 8192   // queries
#define MK 8192   // keys
#define CD 512    // embed dim
#define LN 64    // neighbors per query
#define HH 8      // heads
#define HD 64     // head dim
#define BB 16     // batches
#define KPB 512   // keys per batch
#define QPB 512   // queries per batch

typedef short short8 __attribute__((ext_vector_type(8)));
typedef float floatx4 __attribute__((ext_vector_type(4)));

// fp32 -> bf16 RNE scalar
__device__ __forceinline__ unsigned short f2bf(float x) {
    unsigned int u = __builtin_bit_cast(unsigned int, x);
    return (unsigned short)((u + 0x7FFFu + ((u >> 16) & 1u)) >> 16);
}
// packed pair via HW v_cvt_pk_bf16_f32 on gfx950
__device__ __forceinline__ unsigned int pkbf(float lo, float hi) {
    float2 f; f.x = lo; f.y = hi;
    __hip_bfloat162 h2 = __float22bfloat162_rn(f);
    unsigned int u;
    __builtin_memcpy(&u, &h2, 4);
    return u;
}
// bf16 pair low element -> float (exact)
__device__ __forceinline__ float bflo(unsigned int u) {
    return __builtin_bit_cast(float, u << 16);
}
// bf16 pair high element -> float WITH low-half junk bits: hi*(1+d),
// |d| <= 2^-8 — below bf16's own rounding noise; saves the mask op.
__device__ __forceinline__ float bfhij(unsigned int u) {
    return __builtin_bit_cast(float, u);
}
__device__ __forceinline__ short8 u4s8(uint4 u) {
    short8 s; __builtin_memcpy(&s, &u, 16); return s;
}
// bare transcendentals (avoid ocml range-fixup paths)
__device__ __forceinline__ float exp2v(float x) {
    float r; asm("v_exp_f32 %0, %1" : "=v"(r) : "v"(x)); return r;
}
__device__ __forceinline__ float rcpv(float x) {
    float r; asm("v_rcp_f32 %0, %1" : "=v"(r) : "v"(x)); return r;
}

// async global->LDS, 16B per lane; LDS dest = wave-uniform base + lane*16
__device__ __forceinline__ void gl_lds16(const unsigned short* g, unsigned short* l) {
    __builtin_amdgcn_global_load_lds(
        (const __attribute__((address_space(1))) unsigned int*)g,
        (__attribute__((address_space(3))) unsigned int*)l, 16, 0, 0);
}

// ---------------------------------------------------------------------------
// fp32 -> bf16 conversion prepass (5 segments in one launch)
// ---------------------------------------------------------------------------
struct ConvSeg { const float* src; unsigned short* dst; int n4; };
struct ConvArgs { ConvSeg s[5]; };

__global__ __launch_bounds__(256) void convert_bf16(ConvArgs a) {
    const int seg = blockIdx.y;
    const int i = blockIdx.x * 256 + threadIdx.x;
    if (i >= a.s[seg].n4) return;
    const float4 v = ((const float4*)a.s[seg].src)[i];
    uint2 o; o.x = pkbf(v.x, v.y); o.y = pkbf(v.z, v.w);
    ((uint2*)a.s[seg].dst)[i] = o;
}

// ---------------------------------------------------------------------------
// m97-style bf16 NT GEMM, (MI*16)x128 tile, BK=64, 256 threads = 4 waves.
// MI=8 (128x128) for qkv (R16-proven); MI=4 (64x128) for out_gemm (R17's
// MI=8 switch cost ~4.5us of non-attn time — reverted to the R16 config).
// Staging via global_load_lds_dwordx4 with XOR-swizzled source granule
// (LDS[row][p] = A[row][p ^ (row&7)]) -> conflict-free ds_read_b128.
// ---------------------------------------------------------------------------
template<int MI>
__device__ __forceinline__ void gemm_bf_body(const unsigned short* __restrict__ A,
                                             const unsigned short* __restrict__ W,
                                             const float* __restrict__ bias,
                                             float* __restrict__ outf,
                                             unsigned short* __restrict__ outb,
                                             float scale) {
    __shared__ unsigned short As[MI * 16 * 64];   // 8 or 16 KB
    __shared__ unsigned short Bs[128 * 64];       // 16 KB

    const int tid  = threadIdx.x;
    const int row0 = blockIdx.x * (MI * 16);
    const int col0 = blockIdx.y * 128;

    const int w    = tid >> 6;
    const int lane = tid & 63;
    const int q    = lane >> 4;    // quad
    const int ml   = lane & 15;

    const int sr = lane >> 3;            // 0..7 (== row&7 of the loaded row)
    const int sg = (lane & 7) ^ sr;      // XOR-swizzled source granule
    const unsigned short* Ap = A + (size_t)(row0 + w * (MI * 4) + sr) * CD + sg * 8;
    const unsigned short* Wp = W + (size_t)(col0 + w * 32 + sr) * CD + sg * 8;
    unsigned short* Asw = &As[(w * (MI * 4)) * 64];
    unsigned short* Bsw = &Bs[(w * 32) * 64];

    floatx4 acc[MI][2];
#pragma unroll
    for (int i = 0; i < MI; ++i)
#pragma unroll
        for (int j = 0; j < 2; ++j)
            acc[i][j] = (floatx4){0.f, 0.f, 0.f, 0.f};

    for (int k0 = 0; k0 < CD; k0 += 64) {
        __syncthreads();
#pragma unroll
        for (int i = 0; i < MI / 2; ++i)
            gl_lds16(Ap + (size_t)(i * 8) * CD + k0, Asw + i * 8 * 64);
#pragma unroll
        for (int i = 0; i < 4; ++i)
            gl_lds16(Wp + (size_t)(i * 8) * CD + k0, Bsw + i * 8 * 64);
        __syncthreads();

#pragma unroll
        for (int kw = 0; kw < 2; ++kw) {
            short8 af[MI], bf[2];
            const int gp = ((kw * 4 + q) ^ (ml & 7)) * 8;
#pragma unroll
            for (int mi = 0; mi < MI; ++mi)
                af[mi] = *(const short8*)&As[(mi * 16 + ml) * 64 + gp];
#pragma unroll
            for (int ni = 0; ni < 2; ++ni)
                bf[ni] = *(const short8*)&Bs[(w * 32 + ni * 16 + ml) * 64 + gp];
#pragma unroll
            for (int mi = 0; mi < MI; ++mi)
#pragma unroll
                for (int ni = 0; ni < 2; ++ni)
                    acc[mi][ni] = __builtin_amdgcn_mfma_f32_16x16x32_bf16(
                        af[mi], bf[ni], acc[mi][ni], 0, 0, 0);
        }
    }

    float bv[2];
#pragma unroll
    for (int ni = 0; ni < 2; ++ni)
        bv[ni] = bias[col0 + w * 32 + ni * 16 + ml];
#pragma unroll
    for (int mi = 0; mi < MI; ++mi) {
#pragma unroll
        for (int ni = 0; ni < 2; ++ni) {
            const int cg = col0 + w * 32 + ni * 16 + ml;
#pragma unroll
            for (int rr = 0; rr < 4; ++rr) {
                const int rg = row0 + mi * 16 + q * 4 + rr;
                const float val = (acc[mi][ni][rr] + bv[ni]) * scale;
                if (outb) outb[(size_t)rg * CD + cg] = f2bf(val);
                else      outf[(size_t)rg * CD + cg] = val;
            }
        }
    }
}

// qkv: z=0 -> q bf16 (scale 0.125*log2e folded pre-round: scores come out in
// log2 domain so softmax uses bare v_exp_f32); z=1 -> k; z=2 -> v
#define QSCALE 0.18033688011112042f   // 0.125 * log2(e)

__global__ __launch_bounds__(256, 3) void qkv_gemm(const unsigned short* __restrict__ A_bf,
                                                   const unsigned short* __restrict__ w_bf,
                                                   const float* __restrict__ bias,
                                                   unsigned short* __restrict__ q_bf,
                                                   unsigned short* __restrict__ k_bf,
                                                   unsigned short* __restrict__ v_bf) {
    const int z = blockIdx.z;
    const unsigned short* A = A_bf + (size_t)z * NQ * CD;
    unsigned short* outb = (z == 0) ? q_bf : ((z == 1) ? k_bf : v_bf);
    gemm_bf_body<8>(A, w_bf + (size_t)z * CD * CD, bias + (size_t)z * CD,
                    nullptr, outb, (z == 0) ? QSCALE : 1.0f);
}

// out projection (y<4, 64x128 tile — R16 config) + fused out2 reduce (y==4)
__global__ __launch_bounds__(256) void out_gemm(const unsigned short* __restrict__ A,
                                                const unsigned short* __restrict__ W,
                                                const float* __restrict__ bias,
                                                float* __restrict__ out,
                                                const float* __restrict__ W8,
                                                float* __restrict__ out2) {
    if (blockIdx.y == 4) {
        const size_t base = (size_t)blockIdx.x * 4096 + threadIdx.x;
#pragma unroll
        for (int t = 0; t < 16; ++t) {
            const size_t i = base + (size_t)t * 256;   // NQ*LN total
            float s = 0.f;
#pragma unroll
            for (int h = 0; h < HH; ++h) s += W8[(size_t)h * NQ * LN + i];
            out2[i] = s;
        }
        return;
    }
    gemm_bf_body<4>(A, W, bias, out, nullptr, 1.0f);
}

#define MFMA16(a, b, c) __builtin_amdgcn_mfma_f32_16x16x32_bf16(a, b, c, 0, 0, 0)
#define MK_ -1000.0f

// ---------------------------------------------------------------------------
// Attention (R19 = R18 + packed (g,w) b64 strip). R18 arithmetic: ~42 DS
// instrs/query on one DS pipe shared by 8 waves ≈ 60-70% of the 141K
// cycles — DS-dominated. This round deletes 8 DS instrs/query: the g-strip
// and w-strip merge into ONE uint2 strip at padded index j+(j>>3)
// (write: the jpub-owner lane shfl-fetches g[jpub] and stores {g,w} — one
// bpermute + one b64 write, banks verified distinct; read: 8 b64 reads,
// octet-broadcast + distinct bank-pairs across r8 = conflict-free) instead
// of 2 b32 writes + 16 b32 reads. K-read conflicts (6.7M) are structural
// (8 random 128B rows/octet) and stay. Pair pipeline unchanged.
// ---------------------------------------------------------------------------

// K LDS read: row-major [512][64] with chunk-XOR swizzle
#define KRD(row, ch) (*(const uint4*)&K_s[(row) * 64 + ((((ch) ^ ((row) & 7))) * 8)])

// padded index for the (g,w) uint2 strip: distinct banks for reads & writes
#define GWI(p) ((p) + ((p) >> 3))

// softmax (ownership form): S##0..3 = floatx4 z regs, vm = ballot mask
#define SMX(S, vm, wres) do {                                                 \
    float s0_ = gs1 ? (gs0 ? S##3[0] : S##2[0]) : (gs0 ? S##1[0] : S##0[0]);  \
    float s1_ = gs1 ? (gs0 ? S##3[1] : S##2[1]) : (gs0 ? S##1[1] : S##0[1]);  \
    float s2_ = gs1 ? (gs0 ? S##3[2] : S##2[2]) : (gs0 ? S##1[2] : S##0[2]);  \
    float s3_ = gs1 ? (gs0 ? S##3[3] : S##2[3]) : (gs0 ? S##1[3] : S##0[3]);  \
    const unsigned nib_ = (unsigned)(((vm) >> nibsh) & 0xFull);               \
    s0_ = (nib_ & 1u) ? s0_ : MK_;  s1_ = (nib_ & 2u) ? s1_ : MK_;            \
    s2_ = (nib_ & 4u) ? s2_ : MK_;  s3_ = (nib_ & 8u) ? s3_ : MK_;            \
    float mx_ = fmaxf(fmaxf(s0_, s1_), fmaxf(s2_, s3_));                      \
    mx_ = fmaxf(mx_, __shfl_xor(mx_, 4, 64));                                 \
    mx_ = fmaxf(mx_, __shfl_xor(mx_, 8, 64));                                 \
    mx_ = fmaxf(mx_, __shfl_xor(mx_, 16, 64));                                \
    mx_ = fmaxf(mx_, __shfl_xor(mx_, 32, 64));                                \
    const float e0_ = exp2v(s0_ - mx_), e1_ = exp2v(s1_ - mx_);               \
    const float e2_ = exp2v(s2_ - mx_), e3_ = exp2v(s3_ - mx_);               \
    float sm_ = (e0_ + e1_) + (e2_ + e3_);                                    \
    sm_ += __shfl_xor(sm_, 4, 64);                                            \
    sm_ += __shfl_xor(sm_, 8, 64);                                            \
    sm_ += __shfl_xor(sm_, 16, 64);                                           \
    sm_ += __shfl_xor(sm_, 32, 64);                                           \
    const float rs_ = rcpv(sm_);                                              \
    const float pk_ = rs1 ? (rs0 ? e3_ : e2_) : (rs0 ? e1_ : e0_);            \
    wres = pk_ * rs_;                                                         \
} while (0)

// 8 fma into token-pasted accumulators aX0..aX7 (dim c8*8+e)
#define FMA8X(aX, u, wgt) do {                                                \
    const float w_ = (wgt);                                                   \
    aX##0 = fmaf(w_, bflo((u).x),  aX##0); aX##1 = fmaf(w_, bfhij((u).x), aX##1); \
    aX##2 = fmaf(w_, bflo((u).y),  aX##2); aX##3 = fmaf(w_, bfhij((u).y), aX##3); \
    aX##4 = fmaf(w_, bflo((u).z),  aX##4); aX##5 = fmaf(w_, bfhij((u).z), aX##5); \
    aX##6 = fmaf(w_, bflo((u).w),  aX##6); aX##7 = fmaf(w_, bfhij((u).w), aX##7); \
} while (0)

// PV compute: packed (g,w) pairs from strip gwX -> accs aX0..7
#define PVC(gwX, aX) do {                                                     \
    const uint2 p0_ = gwX[GWI(0 * 8 + r8)];                                   \
    const uint2 p1_ = gwX[GWI(1 * 8 + r8)];                                   \
    const uint2 p2_ = gwX[GWI(2 * 8 + r8)];                                   \
    const uint2 p3_ = gwX[GWI(3 * 8 + r8)];                                   \
    const uint2 p4_ = gwX[GWI(4 * 8 + r8)];                                   \
    const uint2 p5_ = gwX[GWI(5 * 8 + r8)];                                   \
    const uint2 p6_ = gwX[GWI(6 * 8 + r8)];                                   \
    const uint2 p7_ = gwX[GWI(7 * 8 + r8)];                                   \
    const uint4 u0_ = *(const uint4*)&V_s[(int)p0_.x * 64 + c8 * 8];          \
    const uint4 u1_ = *(const uint4*)&V_s[(int)p1_.x * 64 + c8 * 8];          \
    const uint4 u2_ = *(const uint4*)&V_s[(int)p2_.x * 64 + c8 * 8];          \
    const uint4 u3_ = *(const uint4*)&V_s[(int)p3_.x * 64 + c8 * 8];          \
    const uint4 u4_ = *(const uint4*)&V_s[(int)p4_.x * 64 + c8 * 8];          \
    const uint4 u5_ = *(const uint4*)&V_s[(int)p5_.x * 64 + c8 * 8];          \
    const uint4 u6_ = *(const uint4*)&V_s[(int)p6_.x * 64 + c8 * 8];          \
    const uint4 u7_ = *(const uint4*)&V_s[(int)p7_.x * 64 + c8 * 8];          \
    FMA8X(aX, u0_, __builtin_bit_cast(float, p0_.y));                         \
    FMA8X(aX, u1_, __builtin_bit_cast(float, p1_.y));                         \
    FMA8X(aX, u2_, __builtin_bit_cast(float, p2_.y));                         \
    FMA8X(aX, u3_, __builtin_bit_cast(float, p3_.y));                         \
    FMA8X(aX, u4_, __builtin_bit_cast(float, p4_.y));                         \
    FMA8X(aX, u5_, __builtin_bit_cast(float, p5_.y));                         \
    FMA8X(aX, u6_, __builtin_bit_cast(float, p6_.y));                         \
    FMA8X(aX, u7_, __builtin_bit_cast(float, p7_.y));                         \
} while (0)

// reduce accs over r8 via stride-9 LDS, store attn row for query nX
#define REDST(aX, nX) do {                                                    \
    red[lane * 9 + 0] = aX##0; red[lane * 9 + 1] = aX##1;                     \
    red[lane * 9 + 2] = aX##2; red[lane * 9 + 3] = aX##3;                     \
    red[lane * 9 + 4] = aX##4; red[lane * 9 + 5] = aX##5;                     \
    red[lane * 9 + 6] = aX##6; red[lane * 9 + 7] = aX##7;                     \
    const int bc_ = lane >> 3, e_ = lane & 7;                                 \
    const float s_ = (((red[(0 * 8 + bc_) * 9 + e_] + red[(1 * 8 + bc_) * 9 + e_])   \
                     + (red[(2 * 8 + bc_) * 9 + e_] + red[(3 * 8 + bc_) * 9 + e_]))  \
                    + ((red[(4 * 8 + bc_) * 9 + e_] + red[(5 * 8 + bc_) * 9 + e_])   \
                     + (red[(6 * 8 + bc_) * 9 + e_] + red[(7 * 8 + bc_) * 9 + e_])));\
    attn_bf[(size_t)(nX) * CD + head * HD + lane] = f2bf(s_);                 \
} while (0)

__global__ __launch_bounds__(512, 2) void attn_kernel(
    const unsigned short* __restrict__ q_bf,     // NQ*CD bf16 (log2e-scaled)
    const unsigned short* __restrict__ k_bf,     // NQ*CD bf16
    const unsigned short* __restrict__ v_bf,     // NQ*CD bf16
    const int* __restrict__ index_pair,          // (NQ, LN)
    const int* __restrict__ key_batch_cnt,       // (BB,)
    unsigned short* __restrict__ attn_bf,        // NQ*CD bf16
    float* __restrict__ W8) {                    // (HH, NQ, LN) pre-scaled /8
    const int tid  = threadIdx.x;
    const int wid  = tid >> 6;          // 0..7
    const int lane = tid & 63;
    const int bid  = blockIdx.x;        // 0..511
    const int pair = bid & 127;         // (batch, head)
    const int qt   = bid >> 7;          // query quarter 0..3
    const int head = pair & 7;          // == bid % 8 -> XCD co-location
    const int batch= pair >> 3;

    const int quad = lane >> 4, ml = lane & 15;
    const int r8 = lane >> 3, c8 = lane & 7;

    __shared__ unsigned short K_s[KPB * 64];   // 64 KB (chunk-XOR swizzled)
    __shared__ unsigned short V_s[KPB * 64];   // 64 KB (LINEAR — R14 proven)
    __shared__ uint2 gw_s[8][2][72];           // 9.2 KB per-wave A/B {g,w}
    __shared__ float red_s[8 * 64 * 9];        // 18 KB per-wave PV reduce

    // start of this batch's key rows, via prefix scan of key_batch_cnt
    int cnt = (lane < BB) ? key_batch_cnt[lane] : 0;
#pragma unroll
    for (int d = 1; d < BB; d <<= 1) {
        const int t = __shfl_up(cnt, d, 64);
        if (lane >= d) cnt += t;
    }
    const int off0 = (batch > 0) ? __shfl(cnt, batch - 1, 64) : 0;

    // ---- stage K (chunk-XOR swizzled) + V (linear) ------------------------
#pragma unroll
    for (int j = 0; j < 8; ++j) {
        const int rowb = wid * 64 + j * 8;
        const size_t grow = (size_t)(off0 + rowb + r8);
        gl_lds16(k_bf + grow * CD + head * HD + ((c8 ^ r8) * 8), &K_s[rowb * 64]);
        gl_lds16(v_bf + grow * CD + head * HD + (c8 * 8),        &V_s[rowb * 64]);
    }
    __syncthreads();

    // ---- per-wave pair-pipelined query loop -------------------------------
    const int n0 = batch * QPB + qt * 128 + wid * 16;
    const int grp_own = ml >> 2;             // owned score group
    const bool gs0 = ml & 4, gs1 = ml & 8;   // grp_own bits (select)
    const bool rs0 = ml & 1, rs1 = ml & 2;   // owned rr bits (pick)
    const int jpub = grp_own * 16 + quad * 4 + (ml & 3);  // lane->neighbor
    const int nibsh = grp_own * 16 + quad * 4;            // vmask nibble pos
    uint2* gwA = &gw_s[wid][0][0];
    uint2* gwB = &gw_s[wid][1][0];
    float* red = &red_s[wid * 64 * 9];

    int idxA = index_pair[(size_t)n0 * LN + lane];
    int idxB = index_pair[(size_t)(n0 + 1) * LN + lane];
    for (int qi = 0; qi < 16; qi += 2) {
        const int nA = n0 + qi, nB = n0 + qi + 1;
        const int idxA_n = (qi < 14) ? index_pair[(size_t)(nA + 2) * LN + lane] : 0;
        const int idxB_n = (qi < 14) ? index_pair[(size_t)(nB + 2) * LN + lane] : 0;

        const unsigned long long vmA = __ballot(idxA >= 0);
        const int gA = (idxA >= 0) ? idxA : 0;
        const unsigned long long vmB = __ballot(idxB >= 0);
        const int gB = (idxB >= 0) ? idxB : 0;

        // k rows for both queries' MFMA A-frag groups (8 independent shfl)
        const int krA0 = __shfl(gA, ml, 64),      krA1 = __shfl(gA, 16 + ml, 64);
        const int krA2 = __shfl(gA, 32 + ml, 64), krA3 = __shfl(gA, 48 + ml, 64);
        const int krB0 = __shfl(gB, ml, 64),      krB1 = __shfl(gB, 16 + ml, 64);
        const int krB2 = __shfl(gB, 32 + ml, 64), krB3 = __shfl(gB, 48 + ml, 64);

        // q fragments (global 128B rows, L2-hot)
        const unsigned short* qrA = q_bf + (size_t)nA * CD + head * HD;
        const unsigned short* qrB = q_bf + (size_t)nB * CD + head * HD;
        const uint4 qaA0 = *(const uint4*)(qrA + quad * 8);
        const uint4 qaA1 = *(const uint4*)(qrA + 32 + quad * 8);
        const uint4 qaB0 = *(const uint4*)(qrB + quad * 8);
        const uint4 qaB1 = *(const uint4*)(qrB + 32 + quad * 8);

        // K fragments for both queries (16 independent ds_read_b128)
        const uint4 kfA00 = KRD(krA0, quad), kfA01 = KRD(krA0, 4 + quad);
        const uint4 kfA10 = KRD(krA1, quad), kfA11 = KRD(krA1, 4 + quad);
        const uint4 kfA20 = KRD(krA2, quad), kfA21 = KRD(krA2, 4 + quad);
        const uint4 kfA30 = KRD(krA3, quad), kfA31 = KRD(krA3, 4 + quad);
        const uint4 kfB00 = KRD(krB0, quad), kfB01 = KRD(krB0, 4 + quad);
        const uint4 kfB10 = KRD(krB1, quad), kfB11 = KRD(krB1, 4 + quad);
        const uint4 kfB20 = KRD(krB2, quad), kfB21 = KRD(krB2, 4 + quad);
        const uint4 kfB30 = KRD(krB3, quad), kfB31 = KRD(krB3, 4 + quad);

        floatx4 zA0 = (floatx4){0.f,0.f,0.f,0.f}, zA1 = zA0, zA2 = zA0, zA3 = zA0;
        floatx4 zB0 = zA0, zB1 = zA0, zB2 = zA0, zB3 = zA0;
        zA0 = MFMA16(u4s8(kfA00), u4s8(qaA0), zA0);
        zA0 = MFMA16(u4s8(kfA01), u4s8(qaA1), zA0);
        zA1 = MFMA16(u4s8(kfA10), u4s8(qaA0), zA1);
        zA1 = MFMA16(u4s8(kfA11), u4s8(qaA1), zA1);
        zA2 = MFMA16(u4s8(kfA20), u4s8(qaA0), zA2);
        zA2 = MFMA16(u4s8(kfA21), u4s8(qaA1), zA2);
        zA3 = MFMA16(u4s8(kfA30), u4s8(qaA0), zA3);
        zA3 = MFMA16(u4s8(kfA31), u4s8(qaA1), zA3);
        zB0 = MFMA16(u4s8(kfB00), u4s8(qaB0), zB0);
        zB0 = MFMA16(u4s8(kfB01), u4s8(qaB1), zB0);
        zB1 = MFMA16(u4s8(kfB10), u4s8(qaB0), zB1);
        zB1 = MFMA16(u4s8(kfB11), u4s8(qaB1), zB1);
        zB2 = MFMA16(u4s8(kfB20), u4s8(qaB0), zB2);
        zB2 = MFMA16(u4s8(kfB21), u4s8(qaB1), zB2);
        zB3 = MFMA16(u4s8(kfB30), u4s8(qaB0), zB3);
        zB3 = MFMA16(u4s8(kfB31), u4s8(qaB1), zB3);

        // two independent softmax chains (compiler interleaves the shfls)
        float wA, wB;
        SMX(zA, vmA, wA);
        SMX(zB, vmB, wB);
        // pack {g[jpub], w[jpub]} into one padded b64 strip slot
        const int gjA = __shfl(gA, jpub, 64);
        const int gjB = __shfl(gB, jpub, 64);
        uint2 pkA_, pkB_;
        pkA_.x = (unsigned)gjA; pkA_.y = __builtin_bit_cast(unsigned, wA);
        pkB_.x = (unsigned)gjB; pkB_.y = __builtin_bit_cast(unsigned, wB);
        gwA[GWI(jpub)] = pkA_;
        gwB[GWI(jpub)] = pkB_;
        W8[((size_t)head * NQ + nA) * LN + jpub] = wA * 0.125f;
        W8[((size_t)head * NQ + nB) * LN + jpub] = wB * 0.125f;

        // PV for both queries (independent fma chains), then reduce/store
        float aA0=0.f,aA1=0.f,aA2=0.f,aA3=0.f,aA4=0.f,aA5=0.f,aA6=0.f,aA7=0.f;
        float aB0=0.f,aB1=0.f,aB2=0.f,aB3=0.f,aB4=0.f,aB5=0.f,aB6=0.f,aB7=0.f;
        PVC(gwA, aA);
        PVC(gwB, aB);
        REDST(aA, nA);      // same-wave DS ordering: B's red writes follow
        REDST(aB, nB);      // A's red reads in program order — safe reuse

        idxA = idxA_n;
        idxB = idxB_n;
    }
}

// ---------------------------------------------------------------------------
extern "C" void kernel_launch(void* const* d_in, const int* in_sizes, int n_in,
                              void* d_out, int out_size, void* d_ws, size_t ws_size,
                              hipStream_t stream) {
    const float* query   = (const float*)d_in[0];
    const float* key     = (const float*)d_in[1];
    const float* value   = (const float*)d_in[2];
    const float* ipw     = (const float*)d_in[3];   // (3C, C)
    const float* ipb     = (const float*)d_in[4];   // (3C,)
    const float* out_w   = (const float*)d_in[5];   // (C, C)
    const float* out_b   = (const float*)d_in[6];   // (C,)
    const int*   index_pair       = (const int*)d_in[7];
    // d_in[8] = query_batch_cnt (unused: layout is uniform per construction)
    const int*   key_batch_cnt    = (const int*)d_in[9];
    // d_in[10] = index_pair_batch (batch derived from block id)

    float* out = (float*)d_out;                // [attn (NQ*CD) | out2 (NQ*LN)]
    // ws layout (bf16): q 8MB | k 8 | v 8 | A_in 24 | ipw 3 | out_w 1
    unsigned short* q_bf  = (unsigned short*)d_ws;
    unsigned short* k_bf  = q_bf + (size_t)NQ * CD;
    unsigned short* v_bf  = k_bf + (size_t)NQ * CD;
    unsigned short* A_bf  = v_bf + (size_t)NQ * CD;        // 3 * NQ*CD
    unsigned short* w_bf  = A_bf + (size_t)3 * NQ * CD;    // 3 * CD*CD (ipw)
    unsigned short* ow_bf = w_bf + (size_t)3 * CD * CD;    // CD*CD (out_w)
    // attn output (bf16) reuses the A_bf query slot; W8 (16MB fp32) reuses
    // the dead key+value convert slots.
    unsigned short* attn_bf = A_bf;
    float* W8 = (float*)(A_bf + (size_t)NQ * CD);

    // 0) convert inputs/weights to bf16
    ConvArgs ca;
    ca.s[0] = {query, A_bf,                       NQ * CD / 4};
    ca.s[1] = {key,   A_bf + (size_t)NQ * CD,     NQ * CD / 4};
    ca.s[2] = {value, A_bf + (size_t)2 * NQ * CD, NQ * CD / 4};
    ca.s[3] = {ipw,   w_bf,                       3 * CD * CD / 4};
    ca.s[4] = {out_w, ow_bf,                      CD * CD / 4};
    dim3 g0(NQ * CD / 4 / 256, 5);
    convert_bf16<<<g0, 256, 0, stream>>>(ca);

    // 1) q/k/v projections, 128x128 tile (q pre-scaled by 0.125*log2e)
    dim3 g1(NQ / 128, CD / 128, 3);
    qkv_gemm<<<g1, 256, 0, stream>>>(A_bf, w_bf, ipb, q_bf, k_bf, v_bf);

    // 2) gather attention: 512 blocks = (batch,head,qtile), K/V slices in LDS
    attn_kernel<<<512, 512, 0, stream>>>(q_bf, k_bf, v_bf, index_pair,
                                         key_batch_cnt, attn_bf, W8);

    // 3) out projection, 64x128 tile (y<4) + fused out2 head-reduce (y==4)
    dim3 g3(NQ / 64, 5, 1);
    out_gemm<<<g3, 256, 0, stream>>>(attn_bf, ow_bf, out_b, out,
                                     W8, out + (size_t)NQ * CD);
}